// Round 7
// baseline (4395.580 us; speedup 1.0000x reference)
//
#include <hip/hip_runtime.h>

// ---------------------------------------------------------------------------
// Problem constants: B=2, L=1024, D=1024, H=16, DK=DV=64
// ---------------------------------------------------------------------------

#define TILE_M 64
#define TILE_N 64
#define TILE_K 16

struct GemmSlot { const float* W; const float* bias; float* out; int mode; };
struct GemmBatch { GemmSlot s[4]; };

__device__ __forceinline__ float silu_(float x) {
  return x / (1.f + __expf(-x));
}
__device__ __forceinline__ float sigm_(float x) {
  return 1.f / (1.f + __expf(-x));
}
__device__ __forceinline__ float rdl_(float v, int l) {
  return __int_as_float(__builtin_amdgcn_readlane(__float_as_int(v), l));
}

// repeat helpers
#define RPTLO(M) \
  M(0) M(1) M(2) M(3) M(4) M(5) M(6) M(7) \
  M(8) M(9) M(10) M(11) M(12) M(13) M(14) M(15) \
  M(16) M(17) M(18) M(19) M(20) M(21) M(22) M(23) \
  M(24) M(25) M(26) M(27) M(28) M(29) M(30) M(31)
#define RPTHI(M) \
  M(32) M(33) M(34) M(35) M(36) M(37) M(38) M(39) \
  M(40) M(41) M(42) M(43) M(44) M(45) M(46) M(47) \
  M(48) M(49) M(50) M(51) M(52) M(53) M(54) M(55) \
  M(56) M(57) M(58) M(59) M(60) M(61) M(62) M(63)
#define RPT64(M) RPTLO(M) RPTHI(M)

// ---------------------------------------------------------------------------
// Generic fp32 GEMM: C = act(A[M,K] @ W[K,N] + bias), act/store per mode.
// mode 0: raw, linear store; mode 1: silu, linear; mode 2: silu, scatter BHLd
// ---------------------------------------------------------------------------
__global__ __launch_bounds__(256) void gemm_act(
    const float* __restrict__ A, GemmBatch gb, int M, int N, int K)
{
  const GemmSlot sl = gb.s[blockIdx.z];
  const float* __restrict__ W = sl.W;

  __shared__ float As[TILE_K][TILE_M + 4];
  __shared__ float Ws[TILE_K][TILE_N];

  const int tid = threadIdx.x;
  const int bm = blockIdx.x * TILE_M;
  const int bn = blockIdx.y * TILE_N;
  const int tm = (tid >> 4) << 2;
  const int tn = (tid & 15) << 2;
  const int la_r = tid >> 2;
  const int la_c = (tid & 3) << 2;
  const int lw_r = tid >> 4;
  const int lw_c = (tid & 15) << 2;

  float acc[4][4] = {{0.f,0.f,0.f,0.f},{0.f,0.f,0.f,0.f},
                     {0.f,0.f,0.f,0.f},{0.f,0.f,0.f,0.f}};

  for (int kb = 0; kb < K; kb += TILE_K) {
    float4 av = *(const float4*)&A[(size_t)(bm + la_r) * K + kb + la_c];
    float4 wv = *(const float4*)&W[(size_t)(kb + lw_r) * N + bn + lw_c];
    __syncthreads();
    As[la_c + 0][la_r] = av.x;
    As[la_c + 1][la_r] = av.y;
    As[la_c + 2][la_r] = av.z;
    As[la_c + 3][la_r] = av.w;
    *(float4*)&Ws[lw_r][lw_c] = wv;
    __syncthreads();
#pragma unroll
    for (int kk = 0; kk < TILE_K; ++kk) {
      float4 a = *(const float4*)&As[kk][tm];
      float4 b = *(const float4*)&Ws[kk][tn];
      acc[0][0] = fmaf(a.x, b.x, acc[0][0]);
      acc[0][1] = fmaf(a.x, b.y, acc[0][1]);
      acc[0][2] = fmaf(a.x, b.z, acc[0][2]);
      acc[0][3] = fmaf(a.x, b.w, acc[0][3]);
      acc[1][0] = fmaf(a.y, b.x, acc[1][0]);
      acc[1][1] = fmaf(a.y, b.y, acc[1][1]);
      acc[1][2] = fmaf(a.y, b.z, acc[1][2]);
      acc[1][3] = fmaf(a.y, b.w, acc[1][3]);
      acc[2][0] = fmaf(a.z, b.x, acc[2][0]);
      acc[2][1] = fmaf(a.z, b.y, acc[2][1]);
      acc[2][2] = fmaf(a.z, b.z, acc[2][2]);
      acc[2][3] = fmaf(a.z, b.w, acc[2][3]);
      acc[3][0] = fmaf(a.w, b.x, acc[3][0]);
      acc[3][1] = fmaf(a.w, b.y, acc[3][1]);
      acc[3][2] = fmaf(a.w, b.z, acc[3][2]);
      acc[3][3] = fmaf(a.w, b.w, acc[3][3]);
    }
  }

  const float* bias = sl.bias;
  float* out = sl.out;
  const int mode = sl.mode;
#pragma unroll
  for (int i = 0; i < 4; ++i) {
#pragma unroll
    for (int j = 0; j < 4; ++j) {
      int m = bm + tm + i, n = bn + tn + j;
      float c = acc[i][j] + bias[n];
      if (mode >= 1) c = silu_(c);
      if (mode == 2) {
        int h = n >> 6, d = n & 63;
        int b = m >> 10, l = m & 1023;
        out[(((size_t)(b * 16 + h)) * 1024 + l) * 64 + d] = c;
      } else {
        out[(size_t)m * N + n] = c;
      }
    }
  }
}

// ---------------------------------------------------------------------------
// Scalar projections, packed: scl[bh][t][8], slot 0=beta,1=fd,2=sd,3=fg,4=sg
// ---------------------------------------------------------------------------
__global__ __launch_bounds__(256) void scalar_proj(
    const float* __restrict__ hs,
    const float* __restrict__ Wb,  const float* __restrict__ bb,
    const float* __restrict__ Wfd, const float* __restrict__ bfd, const float* __restrict__ fdb,
    const float* __restrict__ Wsd, const float* __restrict__ bsd, const float* __restrict__ sdb,
    const float* __restrict__ Wfg, const float* __restrict__ bfg,
    const float* __restrict__ Wsg, const float* __restrict__ bsg,
    float* __restrict__ scl)
{
  int gid = blockIdx.x * 256 + threadIdx.x;  // < 2048*80
  int m = gid / 80;
  int c = gid - m * 80;
  int type = c >> 4;
  int h = c & 15;
  const float* W; const float* bias; float extra = 0.f;
  switch (type) {
    case 0:  W = Wb;  bias = bb;  break;
    case 1:  W = Wfd; bias = bfd; extra = fdb[h]; break;
    case 2:  W = Wsd; bias = bsd; extra = sdb[h]; break;
    case 3:  W = Wfg; bias = bfg; break;
    default: W = Wsg; bias = bsg; break;
  }
  const float* hrow = hs + (size_t)m * 1024;
  float s = 0.f;
  for (int k2 = 0; k2 < 1024; ++k2)
    s = fmaf(hrow[k2], W[k2 * 16 + h], s);
  s += bias[h] + extra;
  float r = sigm_(s);
  int b = m >> 10, l = m & 1023;
  scl[((size_t)((b * 16 + h) * 1024 + l)) * 8 + type] = r;
}

// ---------------------------------------------------------------------------
// Pre-normalize q and k in place: x *= rsqrt(sum_64(x^2)+1e-6).
// ---------------------------------------------------------------------------
__global__ __launch_bounds__(256) void prenorm(float* __restrict__ p)
{
  int wid = blockIdx.x * 4 + (threadIdx.x >> 6);
  int lane = threadIdx.x & 63;
  size_t idx = (size_t)wid * 64 + lane;
  float x = p[idx];
  float ss = x * x;
#pragma unroll
  for (int d2 = 32; d2 >= 1; d2 >>= 1) ss += __shfl_xor(ss, d2, 64);
  p[idx] = x * rsqrtf(ss + 1e-6f);
}

// ---------------------------------------------------------------------------
// Sequential scan. ONE WAVE per (b,h), but 8 waves CO-RESIDENT per block
// (512 threads, 4 blocks) -> 2 waves per SIMD, so one wave's stalls
// (shfl chains, load latency) are covered by the other's issue.
// __launch_bounds__(512,2) caps unified regs at 256/wave (state ~220 fits).
// State in 128 named scalars; k in wave-uniform loads (SGPRs); q via
// readlane; norms tracked analytically; q/v/sc prefetched at loop TOP
// (full-step latency cover; r6 had only ~300cyc of cover at loop tail).
// ---------------------------------------------------------------------------
__global__ __launch_bounds__(512, 2) void scan_kernel(
    const float* __restrict__ qg, const float* __restrict__ kg, const float* __restrict__ vg,
    const float* __restrict__ scl, const float* __restrict__ rfx, float* __restrict__ og)
{
  const int wid = threadIdx.x >> 6;          // 0..7
  const int bh = blockIdx.x * 8 + wid;       // 0..31
  const int lane = threadIdx.x & 63;         // column index
  const float rf = rfx[0];
  const float rf2 = rf * rf;

#define DECLS(r) float Sf##r = 0.f, Ss##r = 0.f;
  RPT64(DECLS)
#undef DECLS
#define DECLK(r) float kv##r;
  RPT64(DECLK)
#undef DECLK

  const float* kb = kg + (size_t)bh * 65536;
  const float* qb = qg + (size_t)bh * 65536;
  const float* vb = vg + (size_t)bh * 65536;
  const float* sb = scl + (size_t)bh * 8192;
  const int b = bh >> 4, h = bh & 15;
  float* ob = og + (size_t)b * (1024 * 1024) + h * 64;  // + t*1024 + lane

  // preload t = 0: k (uniform), q/v (per-lane), scalars (uniform)
#define LK0(r) kv##r = kb[r];
  RPT64(LK0)
#undef LK0
  float qcur = qb[lane];
  float vv   = vb[lane];
  float4 sc  = *(const float4*)&sb[0];
  float sg4  = sb[4];

  float af = 1.f, as = 1.f;            // lazy scale: actual S = alpha * S'
  float Nf = 0.f, Ns = 0.f, Cc = 0.f;  // analytic ||Sf||^2, ||Ss||^2, <Sf,Ss>

  for (int t = 0; t < 1024; ++t) {
    const int t1 = (t + 1) & 1023;

    // ---- prefetch t+1 q/v/sc at loop TOP: ~full-step latency cover ----
    const float qn  = qb[t1 * 64 + lane];
    const float vn  = vb[t1 * 64 + lane];
    const float4 scn = *(const float4*)&sb[(size_t)t1 * 8];
    const float sgn = sb[(size_t)t1 * 8 + 4];

    const float bt = sc.x, fdt = sc.y, sdt = sc.z, fgt = sc.w, sgt = sg4;

    // ---- pass 1: dots ef = k.Sf', es = k.Ss' (k uniform, in-lane) ----
    float ef = 0.f, es = 0.f;
#define P1(r) ef = fmaf(kv##r, Sf##r, ef); es = fmaf(kv##r, Ss##r, es);
    RPT64(P1)
#undef P1

    // ---- head: decay, error, coefficients ----
    af *= fdt; as *= sdt;
    const float raf = 1.f / af, ras = 1.f / as;
    const float EF = af * ef, ES = as * es;
    const float errf = vv - EF;
    const float errs = vv - ES;
    const float beff = bt * errf * raf;
    const float bess = bt * errs * ras;
    const float cfs = rf * as * raf;
    const float csf = rf * af * ras;

    // ---- A-reduce: 5 quadratic sums, issued before pass2 ----
    float p1 = errf * errf;
    float p2 = errs * errs;
    float p3 = errf * errs;
    float p4 = vv * errf;
    float p5 = vv * errs;
#pragma unroll
    for (int d2 = 32; d2 >= 1; d2 >>= 1) {
      p1 += __shfl_xor(p1, d2, 64);
      p2 += __shfl_xor(p2, d2, 64);
      p3 += __shfl_xor(p3, d2, 64);
      p4 += __shfl_xor(p4, d2, 64);
      p5 += __shfl_xor(p5, d2, 64);
    }

    // ---- pass 2: rank-1 update + resonance combine + q-dot ----
    float of = 0.f, os = 0.f;
#define P2(r) { \
      float sfv = fmaf(kv##r, beff, Sf##r); \
      float svv = fmaf(kv##r, bess, Ss##r); \
      float tf = fmaf(cfs, svv, sfv); \
      float ts = fmaf(csf, sfv, svv); \
      float rq = rdl_(qcur, r); \
      of = fmaf(rq, tf, of); \
      os = fmaf(rq, ts, os); \
      Sf##r = tf; Ss##r = ts; }
    RPTLO(P2)
    // reload k low half for t+1 (kv0..31 dead after the rows above)
    {
      const float* kn = kb + (t1 << 6);
#define LKLO(r) kv##r = kn[r];
      RPTLO(LKLO)
#undef LKLO
    }
    RPTHI(P2)
#undef P2
    {
      const float* kn = kb + (t1 << 6);
#define LKHI(r) kv##r = kn[r];
      RPTHI(LKHI)
#undef LKHI
    }

    // ---- closed-form norm recurrences (A-reduce results now needed) ----
    const float A1 = p4 - p1;
    const float A2 = p5 - p2;
    const float A3 = p1, A4 = p2, A5 = p3;
    const float A67 = p4 + p5 - 2.f * p3;
    const float b2 = bt * bt;
    const float Nfd = fmaf(fdt * fdt, Nf, fmaf(2.f * bt, A1, b2 * A3));
    const float Nsd = fmaf(sdt * sdt, Ns, fmaf(2.f * bt, A2, b2 * A4));
    const float Cd  = fmaf(fdt * sdt, Cc, fmaf(bt, A67, b2 * A5));
    const float NTf = Nfd + 2.f * rf * Cd + rf2 * Nsd;
    const float NTs = Nsd + 2.f * rf * Cd + rf2 * Nfd;
    const float CT  = (1.f + rf2) * Cd + rf * (Nfd + Nsd);
    const bool capf = NTf > 4096.f;
    const bool caps = NTs > 4096.f;
    const float scf = capf ? 64.f * rsqrtf(NTf) : 1.f;
    const float scs = caps ? 64.f * rsqrtf(NTs) : 1.f;
    af *= scf; as *= scs;
    Nf = capf ? 4096.f : NTf;
    Ns = caps ? 4096.f : NTs;
    Cc = scf * scs * CT;

    // ---- output ----
    ob[(size_t)t * 1024 + lane] = fgt * af * of + sgt * as * os;

    // ---- periodic refold to keep alpha in fp32 range ----
    if ((t & 3) == 3) {
#define RFOLD(r) Sf##r *= af; Ss##r *= as;
      RPT64(RFOLD)
#undef RFOLD
      af = 1.f; as = 1.f;
    }

    // ---- rotate pipeline registers ----
    qcur = qn; vv = vn; sc = scn; sg4 = sgn;
  }
}

// ---------------------------------------------------------------------------
// Gated RMSNorm: og = o * rsqrt(mean(o^2)+eps) * onorm_w * silu_g (g pre-silu'd)
// ---------------------------------------------------------------------------
__global__ __launch_bounds__(256) void rms_gate(
    const float* __restrict__ o, const float* __restrict__ gsil,
    const float* __restrict__ onw, float* __restrict__ og)
{
  int gi = blockIdx.x * 4 + (threadIdx.x >> 6);
  int lane = threadIdx.x & 63;
  size_t idx = (size_t)gi * 64 + lane;
  float x = o[idx];
  float ss = x * x;
#pragma unroll
  for (int d2 = 32; d2 >= 1; d2 >>= 1) ss += __shfl_xor(ss, d2, 64);
  float r = rsqrtf(ss * (1.f / 64.f) + 1e-5f);
  og[idx] = x * r * onw[lane] * gsil[idx];
}

// ---------------------------------------------------------------------------
// Host launcher
// ---------------------------------------------------------------------------
extern "C" void kernel_launch(void* const* d_in, const int* in_sizes, int n_in,
                              void* d_out, int out_size, void* d_ws, size_t ws_size,
                              hipStream_t stream)
{
  const float* hs  = (const float*)d_in[0];
  const float* Wq  = (const float*)d_in[1];
  const float* bq  = (const float*)d_in[2];
  const float* Wk  = (const float*)d_in[3];
  const float* bk  = (const float*)d_in[4];
  const float* Wv  = (const float*)d_in[5];
  const float* bv  = (const float*)d_in[6];
  const float* Wb  = (const float*)d_in[7];
  const float* bb  = (const float*)d_in[8];
  const float* Wfd = (const float*)d_in[9];
  const float* bfd = (const float*)d_in[10];
  const float* fdb = (const float*)d_in[11];
  const float* Wsd = (const float*)d_in[12];
  const float* bsd = (const float*)d_in[13];
  const float* sdb = (const float*)d_in[14];
  const float* Wfg = (const float*)d_in[15];
  const float* bfg = (const float*)d_in[16];
  const float* Wsg = (const float*)d_in[17];
  const float* bsg = (const float*)d_in[18];
  const float* Wg  = (const float*)d_in[19];
  const float* bg  = (const float*)d_in[20];
  const float* onw = (const float*)d_in[21];
  const float* Wo  = (const float*)d_in[22];
  const float* bo  = (const float*)d_in[23];
  const float* rfx = (const float*)d_in[24];

  float* ws = (float*)d_ws;
  const size_t TWO_M = (size_t)1 << 21;  // 2M floats = B*H*L*64
  float* q_ws  = ws;                     // q and k contiguous for prenorm
  float* k_ws  = ws + TWO_M;
  float* v_ws  = ws + 2 * TWO_M;
  float* g_ws  = ws + 3 * TWO_M;
  float* o_ws  = ws + 4 * TWO_M;
  float* scl_ws = ws + 5 * TWO_M;        // 32*1024*8 floats packed scalars
  float* og_ws = q_ws;  // reuse q buffer (scan has consumed it)

  // 1) big projections: q,k,v (silu + scatter), g (silu, linear)
  GemmBatch gb1;
  gb1.s[0].W = Wq; gb1.s[0].bias = bq; gb1.s[0].out = q_ws; gb1.s[0].mode = 2;
  gb1.s[1].W = Wk; gb1.s[1].bias = bk; gb1.s[1].out = k_ws; gb1.s[1].mode = 2;
  gb1.s[2].W = Wv; gb1.s[2].bias = bv; gb1.s[2].out = v_ws; gb1.s[2].mode = 2;
  gb1.s[3].W = Wg; gb1.s[3].bias = bg; gb1.s[3].out = g_ws; gb1.s[3].mode = 1;
  gemm_act<<<dim3(32, 16, 4), 256, 0, stream>>>(hs, gb1, 2048, 1024, 1024);

  // 2) per-head scalar projections (packed)
  scalar_proj<<<640, 256, 0, stream>>>(hs, Wb, bb, Wfd, bfd, fdb, Wsd, bsd, sdb,
                                       Wfg, bfg, Wsg, bsg, scl_ws);

  // 3) pre-normalize q,k (contiguous 4M floats = 65536 rows of 64)
  prenorm<<<16384, 256, 0, stream>>>(q_ws);

  // 4) sequential dual-state delta-rule scan: 8 waves/block co-resident
  scan_kernel<<<4, 512, 0, stream>>>(q_ws, k_ws, v_ws, scl_ws, rfx, o_ws);

  // 5) gated RMSNorm
  rms_gate<<<8192, 256, 0, stream>>>(o_ws, g_ws, onw, og_ws);

  // 6) output projection -> d_out
  GemmBatch gb2;
  gb2.s[0].W = Wo; gb2.s[0].bias = bo; gb2.s[0].out = (float*)d_out; gb2.s[0].mode = 0;
  gb2.s[1] = gb2.s[0]; gb2.s[2] = gb2.s[0]; gb2.s[3] = gb2.s[0];
  gemm_act<<<dim3(32, 16, 1), 256, 0, stream>>>(og_ws, gb2, 2048, 1024, 1024);
}

// Round 8
// 1605.212 us; speedup vs baseline: 2.7383x; 2.7383x over previous
//
#include <hip/hip_runtime.h>

// ---------------------------------------------------------------------------
// Problem constants: B=2, L=1024, D=1024, H=16, DK=DV=64
// ---------------------------------------------------------------------------

#define TILE_M 64
#define TILE_N 64
#define TILE_K 16

struct GemmSlot { const float* W; const float* bias; float* out; int mode; };
struct GemmBatch { GemmSlot s[4]; };

__device__ __forceinline__ float silu_(float x) {
  return x / (1.f + __expf(-x));
}
__device__ __forceinline__ float sigm_(float x) {
  return 1.f / (1.f + __expf(-x));
}
__device__ __forceinline__ float rdl_(float v, int l) {
  return __int_as_float(__builtin_amdgcn_readlane(__float_as_int(v), l));
}

// ---------------------------------------------------------------------------
// Generic fp32 GEMM: C = act(A[M,K] @ W[K,N] + bias), act/store per mode.
// mode 0: raw, linear store; mode 1: silu, linear; mode 2: silu, scatter BHLd
// ---------------------------------------------------------------------------
__global__ __launch_bounds__(256) void gemm_act(
    const float* __restrict__ A, GemmBatch gb, int M, int N, int K)
{
  const GemmSlot sl = gb.s[blockIdx.z];
  const float* __restrict__ W = sl.W;

  __shared__ float As[TILE_K][TILE_M + 4];
  __shared__ float Ws[TILE_K][TILE_N];

  const int tid = threadIdx.x;
  const int bm = blockIdx.x * TILE_M;
  const int bn = blockIdx.y * TILE_N;
  const int tm = (tid >> 4) << 2;
  const int tn = (tid & 15) << 2;
  const int la_r = tid >> 2;
  const int la_c = (tid & 3) << 2;
  const int lw_r = tid >> 4;
  const int lw_c = (tid & 15) << 2;

  float acc[4][4] = {{0.f,0.f,0.f,0.f},{0.f,0.f,0.f,0.f},
                     {0.f,0.f,0.f,0.f},{0.f,0.f,0.f,0.f}};

  for (int kb = 0; kb < K; kb += TILE_K) {
    float4 av = *(const float4*)&A[(size_t)(bm + la_r) * K + kb + la_c];
    float4 wv = *(const float4*)&W[(size_t)(kb + lw_r) * N + bn + lw_c];
    __syncthreads();
    As[la_c + 0][la_r] = av.x;
    As[la_c + 1][la_r] = av.y;
    As[la_c + 2][la_r] = av.z;
    As[la_c + 3][la_r] = av.w;
    *(float4*)&Ws[lw_r][lw_c] = wv;
    __syncthreads();
#pragma unroll
    for (int kk = 0; kk < TILE_K; ++kk) {
      float4 a = *(const float4*)&As[kk][tm];
      float4 b = *(const float4*)&Ws[kk][tn];
      acc[0][0] = fmaf(a.x, b.x, acc[0][0]);
      acc[0][1] = fmaf(a.x, b.y, acc[0][1]);
      acc[0][2] = fmaf(a.x, b.z, acc[0][2]);
      acc[0][3] = fmaf(a.x, b.w, acc[0][3]);
      acc[1][0] = fmaf(a.y, b.x, acc[1][0]);
      acc[1][1] = fmaf(a.y, b.y, acc[1][1]);
      acc[1][2] = fmaf(a.y, b.z, acc[1][2]);
      acc[1][3] = fmaf(a.y, b.w, acc[1][3]);
      acc[2][0] = fmaf(a.z, b.x, acc[2][0]);
      acc[2][1] = fmaf(a.z, b.y, acc[2][1]);
      acc[2][2] = fmaf(a.z, b.z, acc[2][2]);
      acc[2][3] = fmaf(a.z, b.w, acc[2][3]);
      acc[3][0] = fmaf(a.w, b.x, acc[3][0]);
      acc[3][1] = fmaf(a.w, b.y, acc[3][1]);
      acc[3][2] = fmaf(a.w, b.z, acc[3][2]);
      acc[3][3] = fmaf(a.w, b.w, acc[3][3]);
    }
  }

  const float* bias = sl.bias;
  float* out = sl.out;
  const int mode = sl.mode;
#pragma unroll
  for (int i = 0; i < 4; ++i) {
#pragma unroll
    for (int j = 0; j < 4; ++j) {
      int m = bm + tm + i, n = bn + tn + j;
      float c = acc[i][j] + bias[n];
      if (mode >= 1) c = silu_(c);
      if (mode == 2) {
        int h = n >> 6, d = n & 63;
        int b = m >> 10, l = m & 1023;
        out[(((size_t)(b * 16 + h)) * 1024 + l) * 64 + d] = c;
      } else {
        out[(size_t)m * N + n] = c;
      }
    }
  }
}

// ---------------------------------------------------------------------------
// Scalar projections, packed: scl[bh][t][8], slot 0=beta,1=fd,2=sd,3=fg,4=sg
// ---------------------------------------------------------------------------
__global__ __launch_bounds__(256) void scalar_proj(
    const float* __restrict__ hs,
    const float* __restrict__ Wb,  const float* __restrict__ bb,
    const float* __restrict__ Wfd, const float* __restrict__ bfd, const float* __restrict__ fdb,
    const float* __restrict__ Wsd, const float* __restrict__ bsd, const float* __restrict__ sdb,
    const float* __restrict__ Wfg, const float* __restrict__ bfg,
    const float* __restrict__ Wsg, const float* __restrict__ bsg,
    float* __restrict__ scl)
{
  int gid = blockIdx.x * 256 + threadIdx.x;  // < 2048*80
  int m = gid / 80;
  int c = gid - m * 80;
  int type = c >> 4;
  int h = c & 15;
  const float* W; const float* bias; float extra = 0.f;
  switch (type) {
    case 0:  W = Wb;  bias = bb;  break;
    case 1:  W = Wfd; bias = bfd; extra = fdb[h]; break;
    case 2:  W = Wsd; bias = bsd; extra = sdb[h]; break;
    case 3:  W = Wfg; bias = bfg; break;
    default: W = Wsg; bias = bsg; break;
  }
  const float* hrow = hs + (size_t)m * 1024;
  float s = 0.f;
  for (int k2 = 0; k2 < 1024; ++k2)
    s = fmaf(hrow[k2], W[k2 * 16 + h], s);
  s += bias[h] + extra;
  float r = sigm_(s);
  int b = m >> 10, l = m & 1023;
  scl[((size_t)((b * 16 + h) * 1024 + l)) * 8 + type] = r;
}

// ---------------------------------------------------------------------------
// Pre-normalize q and k in place: x *= rsqrt(sum_64(x^2)+1e-6).
// ---------------------------------------------------------------------------
__global__ __launch_bounds__(256) void prenorm(float* __restrict__ p)
{
  int wid = blockIdx.x * 4 + (threadIdx.x >> 6);
  int lane = threadIdx.x & 63;
  size_t idx = (size_t)wid * 64 + lane;
  float x = p[idx];
  float ss = x * x;
#pragma unroll
  for (int d2 = 32; d2 >= 1; d2 >>= 1) ss += __shfl_xor(ss, d2, 64);
  p[idx] = x * rsqrtf(ss + 1e-6f);
}

// ---------------------------------------------------------------------------
// Sequential scan, v8: 4 waves per (b,h), 32 blocks x 256 threads.
// Wave w owns state ROWS [16w,16w+16); lane = column. State = 16-float
// arrays (PROVEN to stay in VGPRs: r2 pattern, VGPR=48). k/q row values
// come from per-lane loads + readlane (no LDS publish). Norms tracked
// analytically (r6-proven recurrences) -> only TWO LDS exchanges + TWO
// barriers per step: (1) ef/es partial dots, (2) of/os partial outputs.
// The in-wave 5-value A-shfl-reduce overlaps pass2.
// ---------------------------------------------------------------------------
__global__ __launch_bounds__(256) void scan_kernel(
    const float* __restrict__ qg, const float* __restrict__ kg, const float* __restrict__ vg,
    const float* __restrict__ scl, const float* __restrict__ rfx, float* __restrict__ og)
{
  const int bh = blockIdx.x;     // 0..31
  const int tid = threadIdx.x;
  const int lane = tid & 63;     // column index
  const int w = tid >> 6;        // wave id: rows [16w, 16w+16)
  const float rf = rfx[0];
  const float rf2 = rf * rf;

  __shared__ float2 pA[4][64];   // exchange 1: ef/es partials
  __shared__ float2 pB[4][64];   // exchange 2: of/os partials

  float Sf[16], Ss[16];
#pragma unroll
  for (int j = 0; j < 16; ++j) { Sf[j] = 0.f; Ss[j] = 0.f; }

  const float* kb = kg + (size_t)bh * 65536;
  const float* qb = qg + (size_t)bh * 65536;
  const float* vb = vg + (size_t)bh * 65536;
  const float* sb = scl + (size_t)bh * 8192;
  const int b = bh >> 4, h = bh & 15;
  float* ob = og + (size_t)b * (1024 * 1024) + h * 64;  // + t*1024 + lane

  // preload t = 0
  float kcur = kb[lane];
  float qcur = qb[lane];
  float vv   = vb[lane];
  float4 sc  = *(const float4*)&sb[0];
  float sg4  = sb[4];

  float af = 1.f, as = 1.f;            // lazy scale: actual S = alpha * S'
  float Nf = 0.f, Ns = 0.f, Cc = 0.f;  // analytic ||Sf||^2, ||Ss||^2, <Sf,Ss>

  for (int t = 0; t < 1024; ++t) {
    const int t1 = (t + 1) & 1023;
    // ---- prefetch t+1 (latency covered by the whole step) ----
    const float kn = kb[t1 * 64 + lane];
    const float qn = qb[t1 * 64 + lane];
    const float vn = vb[t1 * 64 + lane];
    const float4 scn = *(const float4*)&sb[(size_t)t1 * 8];
    const float sgn = sb[(size_t)t1 * 8 + 4];

    const float bt = sc.x, fdt = sc.y, sdt = sc.z, fgt = sc.w, sgt = sg4;

    // ---- broadcast k rows for this wave's 16 rows ----
    float kr[16];
#pragma unroll
    for (int j = 0; j < 16; ++j) kr[j] = rdl_(kcur, w * 16 + j);

    // ---- pass 1: partial dots over my 16 rows ----
    float ef = 0.f, es = 0.f;
#pragma unroll
    for (int j = 0; j < 16; ++j) {
      ef = fmaf(kr[j], Sf[j], ef);
      es = fmaf(kr[j], Ss[j], es);
    }
    pA[w][lane] = make_float2(ef, es);
    __syncthreads();  // B1
    {
      float2 a0 = pA[0][lane], a1 = pA[1][lane], a2 = pA[2][lane], a3 = pA[3][lane];
      ef = (a0.x + a1.x) + (a2.x + a3.x);
      es = (a0.y + a1.y) + (a2.y + a3.y);
    }

    // ---- head: decay, error, coefficients (all block-uniform per column) ----
    af *= fdt; as *= sdt;
    const float raf = 1.f / af, ras = 1.f / as;
    const float EF = af * ef, ES = as * es;
    const float errf = vv - EF;
    const float errs = vv - ES;
    const float beff = bt * errf * raf;
    const float bess = bt * errs * ras;
    const float cfs = rf * as * raf;
    const float csf = rf * af * ras;

    // ---- A-reduce: 5 quadratic sums (in-wave shfl, overlaps pass 2) ----
    float p1 = errf * errf;
    float p2 = errs * errs;
    float p3 = errf * errs;
    float p4 = vv * errf;
    float p5 = vv * errs;
#pragma unroll
    for (int d2 = 32; d2 >= 1; d2 >>= 1) {
      p1 += __shfl_xor(p1, d2, 64);
      p2 += __shfl_xor(p2, d2, 64);
      p3 += __shfl_xor(p3, d2, 64);
      p4 += __shfl_xor(p4, d2, 64);
      p5 += __shfl_xor(p5, d2, 64);
    }

    // ---- pass 2: rank-1 update + resonance combine + partial q-dots ----
    float qr[16];
#pragma unroll
    for (int j = 0; j < 16; ++j) qr[j] = rdl_(qcur, w * 16 + j);
    float of = 0.f, os = 0.f;
#pragma unroll
    for (int j = 0; j < 16; ++j) {
      float sfv = fmaf(kr[j], beff, Sf[j]);
      float svv = fmaf(kr[j], bess, Ss[j]);
      float tf = fmaf(cfs, svv, sfv);
      float ts = fmaf(csf, sfv, svv);
      of = fmaf(qr[j], tf, of);
      os = fmaf(qr[j], ts, os);
      Sf[j] = tf; Ss[j] = ts;
    }
    pB[w][lane] = make_float2(of, os);
    __syncthreads();  // B2
    {
      float2 b0 = pB[0][lane], b1 = pB[1][lane], b2v = pB[2][lane], b3 = pB[3][lane];
      of = (b0.x + b1.x) + (b2v.x + b3.x);
      os = (b0.y + b1.y) + (b2v.y + b3.y);
    }

    // ---- closed-form norm recurrences (r6-proven) ----
    const float A1 = p4 - p1;
    const float A2 = p5 - p2;
    const float A3 = p1, A4 = p2, A5 = p3;
    const float A67 = p4 + p5 - 2.f * p3;
    const float b2s = bt * bt;
    const float Nfd = fmaf(fdt * fdt, Nf, fmaf(2.f * bt, A1, b2s * A3));
    const float Nsd = fmaf(sdt * sdt, Ns, fmaf(2.f * bt, A2, b2s * A4));
    const float Cd  = fmaf(fdt * sdt, Cc, fmaf(bt, A67, b2s * A5));
    const float NTf = Nfd + 2.f * rf * Cd + rf2 * Nsd;
    const float NTs = Nsd + 2.f * rf * Cd + rf2 * Nfd;
    const float CT  = (1.f + rf2) * Cd + rf * (Nfd + Nsd);
    const bool capf = NTf > 4096.f;
    const bool caps = NTs > 4096.f;
    const float scf = capf ? 64.f * rsqrtf(NTf) : 1.f;
    const float scs = caps ? 64.f * rsqrtf(NTs) : 1.f;
    af *= scf; as *= scs;
    Nf = capf ? 4096.f : NTf;
    Ns = caps ? 4096.f : NTs;
    Cc = scf * scs * CT;

    // ---- output (wave 0 stores the full row) ----
    if (w == 0) ob[(size_t)t * 1024 + lane] = fgt * af * of + sgt * as * os;

    // ---- periodic refold to keep alpha in fp32 range ----
    if ((t & 3) == 3) {
#pragma unroll
      for (int j = 0; j < 16; ++j) { Sf[j] *= af; Ss[j] *= as; }
      af = 1.f; as = 1.f;
    }

    // ---- rotate pipeline registers ----
    kcur = kn; qcur = qn; vv = vn; sc = scn; sg4 = sgn;
  }
}

// ---------------------------------------------------------------------------
// Gated RMSNorm: og = o * rsqrt(mean(o^2)+eps) * onorm_w * silu_g (g pre-silu'd)
// ---------------------------------------------------------------------------
__global__ __launch_bounds__(256) void rms_gate(
    const float* __restrict__ o, const float* __restrict__ gsil,
    const float* __restrict__ onw, float* __restrict__ og)
{
  int gi = blockIdx.x * 4 + (threadIdx.x >> 6);
  int lane = threadIdx.x & 63;
  size_t idx = (size_t)gi * 64 + lane;
  float x = o[idx];
  float ss = x * x;
#pragma unroll
  for (int d2 = 32; d2 >= 1; d2 >>= 1) ss += __shfl_xor(ss, d2, 64);
  float r = rsqrtf(ss * (1.f / 64.f) + 1e-5f);
  og[idx] = x * r * onw[lane] * gsil[idx];
}

// ---------------------------------------------------------------------------
// Host launcher
// ---------------------------------------------------------------------------
extern "C" void kernel_launch(void* const* d_in, const int* in_sizes, int n_in,
                              void* d_out, int out_size, void* d_ws, size_t ws_size,
                              hipStream_t stream)
{
  const float* hs  = (const float*)d_in[0];
  const float* Wq  = (const float*)d_in[1];
  const float* bq  = (const float*)d_in[2];
  const float* Wk  = (const float*)d_in[3];
  const float* bk  = (const float*)d_in[4];
  const float* Wv  = (const float*)d_in[5];
  const float* bv  = (const float*)d_in[6];
  const float* Wb  = (const float*)d_in[7];
  const float* bb  = (const float*)d_in[8];
  const float* Wfd = (const float*)d_in[9];
  const float* bfd = (const float*)d_in[10];
  const float* fdb = (const float*)d_in[11];
  const float* Wsd = (const float*)d_in[12];
  const float* bsd = (const float*)d_in[13];
  const float* sdb = (const float*)d_in[14];
  const float* Wfg = (const float*)d_in[15];
  const float* bfg = (const float*)d_in[16];
  const float* Wsg = (const float*)d_in[17];
  const float* bsg = (const float*)d_in[18];
  const float* Wg  = (const float*)d_in[19];
  const float* bg  = (const float*)d_in[20];
  const float* onw = (const float*)d_in[21];
  const float* Wo  = (const float*)d_in[22];
  const float* bo  = (const float*)d_in[23];
  const float* rfx = (const float*)d_in[24];

  float* ws = (float*)d_ws;
  const size_t TWO_M = (size_t)1 << 21;  // 2M floats = B*H*L*64
  float* q_ws  = ws;                     // q and k contiguous for prenorm
  float* k_ws  = ws + TWO_M;
  float* v_ws  = ws + 2 * TWO_M;
  float* g_ws  = ws + 3 * TWO_M;
  float* o_ws  = ws + 4 * TWO_M;
  float* scl_ws = ws + 5 * TWO_M;        // 32*1024*8 floats packed scalars
  float* og_ws = q_ws;  // reuse q buffer (scan has consumed it)

  // 1) big projections: q,k,v (silu + scatter), g (silu, linear)
  GemmBatch gb1;
  gb1.s[0].W = Wq; gb1.s[0].bias = bq; gb1.s[0].out = q_ws; gb1.s[0].mode = 2;
  gb1.s[1].W = Wk; gb1.s[1].bias = bk; gb1.s[1].out = k_ws; gb1.s[1].mode = 2;
  gb1.s[2].W = Wv; gb1.s[2].bias = bv; gb1.s[2].out = v_ws; gb1.s[2].mode = 2;
  gb1.s[3].W = Wg; gb1.s[3].bias = bg; gb1.s[3].out = g_ws; gb1.s[3].mode = 1;
  gemm_act<<<dim3(32, 16, 4), 256, 0, stream>>>(hs, gb1, 2048, 1024, 1024);

  // 2) per-head scalar projections (packed)
  scalar_proj<<<640, 256, 0, stream>>>(hs, Wb, bb, Wfd, bfd, fdb, Wsd, bsd, sdb,
                                       Wfg, bfg, Wsg, bsg, scl_ws);

  // 3) pre-normalize q,k (contiguous 4M floats = 65536 rows of 64)
  prenorm<<<16384, 256, 0, stream>>>(q_ws);

  // 4) sequential dual-state delta-rule scan: 4 waves per (b,h)
  scan_kernel<<<32, 256, 0, stream>>>(q_ws, k_ws, v_ws, scl_ws, rfx, o_ws);

  // 5) gated RMSNorm
  rms_gate<<<8192, 256, 0, stream>>>(o_ws, g_ws, onw, og_ws);

  // 6) output projection -> d_out
  GemmBatch gb2;
  gb2.s[0].W = Wo; gb2.s[0].bias = bo; gb2.s[0].out = (float*)d_out; gb2.s[0].mode = 0;
  gb2.s[1] = gb2.s[0]; gb2.s[2] = gb2.s[0]; gb2.s[3] = gb2.s[0];
  gemm_act<<<dim3(32, 16, 1), 256, 0, stream>>>(og_ws, gb2, 2048, 1024, 1024);
}